// Round 1
// baseline (964.895 us; speedup 1.0000x reference)
//
#include <hip/hip_runtime.h>

// GRU encoder: B=64, T=512, F=64, H=256, D=64.
//   k1: xproj = x @ kernel + bias -> f16 in d_ws (unchanged, ~80us).
//   k2: per-batch scan, 64 blocks x 1024 threads.
//       New structure: 8-way k-split (chunk bits on lane bits {0,1,3}),
//       h slice fully register-resident (2 halves of 2x int4), cross-chunk
//       reduction via DPP butterfly (xor1/xor2/xor8), gates fused into the
//       same phase (16 lanes/wave own one column each), ONE barrier/step.
//       No part[] LDS, no xrow LDS; h double-buffered as f16 in 1.25 KB LDS.

typedef _Float16 half2_t __attribute__((ext_vector_type(2)));
typedef _Float16 f16x4_t __attribute__((ext_vector_type(4)));

#define LOG2E 1.4426950408889634f

__device__ __forceinline__ float fast_sigmoid(float x) {
  float e = __builtin_amdgcn_exp2f(-x * LOG2E);
  return __builtin_amdgcn_rcpf(1.0f + e);
}
__device__ __forceinline__ float fast_tanh(float x) {
  float e = __builtin_amdgcn_exp2f(x * (2.0f * LOG2E));
  return 1.0f - 2.0f * __builtin_amdgcn_rcpf(1.0f + e);
}

// v += lane-shuffled(v) via DPP (VALU-only butterfly step, no LDS pipe).
template <int CTRL>
__device__ __forceinline__ float dpp_xor_add(float v) {
  int s = __builtin_amdgcn_update_dpp(0, __builtin_bit_cast(int, v), CTRL,
                                      0xF, 0xF, false);
  return v + __builtin_bit_cast(float, s);
}

// ---------------------------------------------------------------------------
// Kernel 1: xproj GEMM.  C(32768x768) = A(32768x64) @ B(64x768) + bias.
// (unchanged from previous round)
// ---------------------------------------------------------------------------
__global__ __launch_bounds__(256, 4) void xproj_gemm(
    const float* __restrict__ x, const float* __restrict__ kmat,
    const float* __restrict__ bias, _Float16* __restrict__ xp) {
  __shared__ half2_t As2[32][132];  // [kpair][row]
  __shared__ half2_t Bs2[32][132];  // [kpair][col]
  const int tid = threadIdx.x;
  const int rb = blockIdx.x * 128;
  const int cb = blockIdx.y * 128;

  {
    const int k4 = (tid & 15) * 4;
    const int r0 = tid >> 4;
#pragma unroll
    for (int p = 0; p < 8; ++p) {
      int r = r0 + p * 16;
      float4 v = *(const float4*)(x + (size_t)(rb + r) * 64 + k4);
      half2_t lo, hi;
      lo[0] = (_Float16)v.x; lo[1] = (_Float16)v.y;
      hi[0] = (_Float16)v.z; hi[1] = (_Float16)v.w;
      As2[k4 / 2][r] = lo;
      As2[k4 / 2 + 1][r] = hi;
    }
  }
  {
    const int c4 = (tid & 31) * 4;
    const int kp0 = tid >> 5;
#pragma unroll
    for (int p = 0; p < 4; ++p) {
      int kp = kp0 + p * 8;
      float4 va = *(const float4*)(kmat + (size_t)(2 * kp) * 768 + cb + c4);
      float4 vb = *(const float4*)(kmat + (size_t)(2 * kp + 1) * 768 + cb + c4);
      half2_t o0, o1, o2, o3;
      o0[0] = (_Float16)va.x; o0[1] = (_Float16)vb.x;
      o1[0] = (_Float16)va.y; o1[1] = (_Float16)vb.y;
      o2[0] = (_Float16)va.z; o2[1] = (_Float16)vb.z;
      o3[0] = (_Float16)va.w; o3[1] = (_Float16)vb.w;
      Bs2[kp][c4 + 0] = o0;
      Bs2[kp][c4 + 1] = o1;
      Bs2[kp][c4 + 2] = o2;
      Bs2[kp][c4 + 3] = o3;
    }
  }
  __syncthreads();

  const int tx = tid & 15, ty = tid >> 4;
  const int r0 = ty * 8;
  const int c0 = tx * 4;
  float acc[8][8];
  {
    float4 b0 = *(const float4*)(bias + cb + c0);
    float4 b1 = *(const float4*)(bias + cb + 64 + c0);
    float bz[8] = {b0.x, b0.y, b0.z, b0.w, b1.x, b1.y, b1.z, b1.w};
#pragma unroll
    for (int i = 0; i < 8; ++i)
#pragma unroll
      for (int j = 0; j < 8; ++j) acc[i][j] = bz[j];
  }

#pragma unroll 2
  for (int kp = 0; kp < 32; ++kp) {
    half2_t a2[8], b2[8];
    *(int4*)(&a2[0]) = *(const int4*)(&As2[kp][r0]);
    *(int4*)(&a2[4]) = *(const int4*)(&As2[kp][r0 + 4]);
    *(int2*)(&b2[0]) = *(const int2*)(&Bs2[kp][c0]);
    *(int2*)(&b2[2]) = *(const int2*)(&Bs2[kp][c0 + 2]);
    *(int2*)(&b2[4]) = *(const int2*)(&Bs2[kp][64 + c0]);
    *(int2*)(&b2[6]) = *(const int2*)(&Bs2[kp][64 + c0 + 2]);
#pragma unroll
    for (int i = 0; i < 8; ++i)
#pragma unroll
      for (int j = 0; j < 8; ++j)
        acc[i][j] = __builtin_amdgcn_fdot2(a2[i], b2[j], acc[i][j], false);
  }

#pragma unroll
  for (int i = 0; i < 8; ++i) {
    f16x4_t o0, o1;
#pragma unroll
    for (int j = 0; j < 4; ++j) {
      o0[j] = (_Float16)acc[i][j];
      o1[j] = (_Float16)acc[i][4 + j];
    }
    _Float16* dst = xp + (size_t)(rb + r0 + i) * 768 + cb;
    *(f16x4_t*)(dst + c0) = o0;
    *(f16x4_t*)(dst + 64 + c0) = o1;
  }
}

// ---------------------------------------------------------------------------
// Kernel 2: GRU scan. One block per batch. 1024 threads = 16 waves.
// Lane-bit layout: chunk c = bits {l0,l1,l3} (8 k-chunks of 32), column
// sub-index = bits {l2,l4,l5} (+wave*8). Thread holds W_rec[k in c*32..+32)
// for 6 outputs (3 gates x cols {cidx, cidx+128}) as 96 f16 pairs in VGPRs.
// Per step: 96 fdot2 on register-resident h -> DPP butterfly over c ->
// lanes (l&3)==0 compute gates for col = cidx + l3*128 -> ds_write h ->
// ONE __syncthreads.
// ---------------------------------------------------------------------------
#define DOT4(U, J)                                                \
  do {                                                            \
    half2_t p0 = __builtin_bit_cast(half2_t, (U).x);              \
    half2_t p1 = __builtin_bit_cast(half2_t, (U).y);              \
    half2_t p2 = __builtin_bit_cast(half2_t, (U).z);              \
    half2_t p3 = __builtin_bit_cast(half2_t, (U).w);               \
    a0 = __builtin_amdgcn_fdot2(p0, w2[0][(J) + 0], a0, false);   \
    a0 = __builtin_amdgcn_fdot2(p1, w2[0][(J) + 1], a0, false);   \
    a0 = __builtin_amdgcn_fdot2(p2, w2[0][(J) + 2], a0, false);   \
    a0 = __builtin_amdgcn_fdot2(p3, w2[0][(J) + 3], a0, false);   \
    a1 = __builtin_amdgcn_fdot2(p0, w2[1][(J) + 0], a1, false);   \
    a1 = __builtin_amdgcn_fdot2(p1, w2[1][(J) + 1], a1, false);   \
    a1 = __builtin_amdgcn_fdot2(p2, w2[1][(J) + 2], a1, false);   \
    a1 = __builtin_amdgcn_fdot2(p3, w2[1][(J) + 3], a1, false);   \
    a2 = __builtin_amdgcn_fdot2(p0, w2[2][(J) + 0], a2, false);   \
    a2 = __builtin_amdgcn_fdot2(p1, w2[2][(J) + 1], a2, false);   \
    a2 = __builtin_amdgcn_fdot2(p2, w2[2][(J) + 2], a2, false);   \
    a2 = __builtin_amdgcn_fdot2(p3, w2[2][(J) + 3], a2, false);   \
    a3 = __builtin_amdgcn_fdot2(p0, w2[3][(J) + 0], a3, false);   \
    a3 = __builtin_amdgcn_fdot2(p1, w2[3][(J) + 1], a3, false);   \
    a3 = __builtin_amdgcn_fdot2(p2, w2[3][(J) + 2], a3, false);   \
    a3 = __builtin_amdgcn_fdot2(p3, w2[3][(J) + 3], a3, false);   \
    a4 = __builtin_amdgcn_fdot2(p0, w2[4][(J) + 0], a4, false);   \
    a4 = __builtin_amdgcn_fdot2(p1, w2[4][(J) + 1], a4, false);   \
    a4 = __builtin_amdgcn_fdot2(p2, w2[4][(J) + 2], a4, false);   \
    a4 = __builtin_amdgcn_fdot2(p3, w2[4][(J) + 3], a4, false);   \
    a5 = __builtin_amdgcn_fdot2(p0, w2[5][(J) + 0], a5, false);   \
    a5 = __builtin_amdgcn_fdot2(p1, w2[5][(J) + 1], a5, false);   \
    a5 = __builtin_amdgcn_fdot2(p2, w2[5][(J) + 2], a5, false);   \
    a5 = __builtin_amdgcn_fdot2(p3, w2[5][(J) + 3], a5, false);   \
  } while (0)

__global__ __launch_bounds__(1024, 4) void gru_scan(
    const _Float16* __restrict__ xp, const float* __restrict__ wr,
    const float* __restrict__ dw, const float* __restrict__ db,
    float* __restrict__ out, float* __restrict__ state) {
  // h double buffer: [buf][chunk][32 used + 8 pad] f16. Pad 40 -> chunk
  // stride 80 B: the 8 broadcast ds_read_b128 land on disjoint bank sets,
  // and every chunk base is 16 B aligned.
  __shared__ alignas(16) _Float16 hh[2][8][40];
  __shared__ float hbuf[256];

  const int tid = threadIdx.x;
  const int b = blockIdx.x;
  const int lane = tid & 63;
  const int wave = tid >> 6;
  const int c = (lane & 3) | ((lane >> 1) & 4);              // chunk 0..7
  const int sidx = ((lane >> 2) & 1) | ((lane >> 3) & 6);    // 0..7
  const int cidx = wave * 8 + sidx;                          // 0..127
  const int hb = (lane >> 3) & 1;          // column-half select (gate lanes)
  const bool gl = ((lane & 3) == 0);       // 16 gate lanes per wave
  const int col = cidx + hb * 128;         // this gate lane's output column

  // --- W_rec fragment: w2[q][j], q = hb*3+g, pair j covers k = c*32+2j.
  half2_t w2[6][16];
#pragma unroll
  for (int q = 0; q < 6; ++q) {
    const int g = q % 3, hbq = q / 3;
    const float* wp = wr + (size_t)(c * 32) * 768 + g * 256 + cidx + hbq * 128;
#pragma unroll
    for (int j = 0; j < 16; ++j) {
      half2_t p;
      p[0] = (_Float16)wp[(size_t)(2 * j) * 768];
      p[1] = (_Float16)wp[(size_t)(2 * j + 1) * 768];
      w2[q][j] = p;
    }
  }

  if (tid < 640) ((_Float16*)hh)[tid] = (_Float16)0.0f;
  __syncthreads();

  const _Float16* xp_b = xp + (size_t)b * 512 * 768;  // uniform base (SGPR)
  float* out_b = out + (size_t)b * 512 * 256;         // uniform base (SGPR)

  float hprev = 0.0f;
  int buf = 0;

#pragma unroll 1
  for (int t = 0; t < 512; ++t) {
    // Gate lanes: deferred store of h(t-1) + x prefetch for this step.
    // Issued at step top -> full-step latency cover before the barrier
    // drains vmcnt / before x is consumed in the gate phase.
    _Float16 x0h = (_Float16)0.0f, x1h = (_Float16)0.0f, x2h = (_Float16)0.0f;
    if (gl) {
      if (t) out_b[(size_t)(t - 1) * 256 + col] = hprev;
      const _Float16* xr_ = xp_b + (size_t)t * 768 + col;
      x0h = xr_[0];
      x1h = xr_[256];
      x2h = xr_[512];
    }

    const int4* hp = (const int4*)hh[buf][c];
    float a0 = 0.f, a1 = 0.f, a2 = 0.f, a3 = 0.f, a4 = 0.f, a5 = 0.f;
    {
      int4 u0 = hp[0];
      int4 u1 = hp[1];
      DOT4(u0, 0);
      DOT4(u1, 4);
    }
    // Keep the second h half-read from being hoisted: caps live h at 8
    // dwords so the full kernel stays under the 128-VGPR / 16-wave limit.
    __builtin_amdgcn_sched_barrier(0);
    {
      int4 u2 = hp[2];
      int4 u3 = hp[3];
      DOT4(u2, 8);
      DOT4(u3, 12);
    }

    // Cross-chunk reduction: chunk bits are lane bits {0,1,3} ->
    // quad_perm xor1, quad_perm xor2, row_ror:8 (== xor8). VALU-only.
    a0 = dpp_xor_add<0xB1>(a0);
    a1 = dpp_xor_add<0xB1>(a1);
    a2 = dpp_xor_add<0xB1>(a2);
    a3 = dpp_xor_add<0xB1>(a3);
    a4 = dpp_xor_add<0xB1>(a4);
    a5 = dpp_xor_add<0xB1>(a5);
    a0 = dpp_xor_add<0x4E>(a0);
    a1 = dpp_xor_add<0x4E>(a1);
    a2 = dpp_xor_add<0x4E>(a2);
    a3 = dpp_xor_add<0x4E>(a3);
    a4 = dpp_xor_add<0x4E>(a4);
    a5 = dpp_xor_add<0x4E>(a5);
    a0 = dpp_xor_add<0x128>(a0);
    a1 = dpp_xor_add<0x128>(a1);
    a2 = dpp_xor_add<0x128>(a2);
    a3 = dpp_xor_add<0x128>(a3);
    a4 = dpp_xor_add<0x128>(a4);
    a5 = dpp_xor_add<0x128>(a5);

    // Gates: each gate lane owns one column; its 3 sums are in-lane.
    if (gl) {
      float rz = hb ? a3 : a0;
      float rr = hb ? a4 : a1;
      float rh = hb ? a5 : a2;
      float z = fast_sigmoid((float)x0h + rz);
      float r = fast_sigmoid((float)x1h + rr);
      float hcand = fast_tanh((float)x2h + r * rh);
      float hnew = z * hprev + (1.0f - z) * hcand;
      hprev = hnew;
      hh[buf ^ 1][col >> 5][col & 31] = (_Float16)hnew;
    }
    __syncthreads();  // single barrier per step (double-buffered h)
    buf ^= 1;
  }

  if (gl) {
    out_b[(size_t)511 * 256 + col] = hprev;
    hbuf[col] = hprev;
  }
  __syncthreads();

  // --- dense head: state[b,:] = tanh(h_last @ dense_w + dense_b)
  if (tid < 64) {
    float acc = db[tid];
#pragma unroll 8
    for (int k = 0; k < 256; ++k) acc = fmaf(hbuf[k], dw[k * 64 + tid], acc);
    state[(size_t)b * 64 + tid] = fast_tanh(acc);
  }
}

// ---------------------------------------------------------------------------
extern "C" void kernel_launch(void* const* d_in, const int* in_sizes, int n_in,
                              void* d_out, int out_size, void* d_ws,
                              size_t ws_size, hipStream_t stream) {
  const float* x = (const float*)d_in[0];     // (64,512,64)
  const float* kmat = (const float*)d_in[1];  // (64,768)
  const float* wr = (const float*)d_in[2];    // (256,768)
  const float* bias = (const float*)d_in[3];  // (768,)
  const float* dw = (const float*)d_in[4];    // (256,64)
  const float* db = (const float*)d_in[5];    // (64,)

  float* out = (float*)d_out;                   // (64,512,256)
  float* state = out + (size_t)64 * 512 * 256;  // (64,64)
  _Float16* xp = (_Float16*)d_ws;               // 64*512*768 f16 = 48 MiB

  dim3 gg(32768 / 128, 768 / 128);
  xproj_gemm<<<gg, 256, 0, stream>>>(x, kmat, bias, xp);
  gru_scan<<<64, 1024, 0, stream>>>(xp, wr, dw, db, out, state);
}

// Round 2
// 661.857 us; speedup vs baseline: 1.4579x; 1.4579x over previous
//
#include <hip/hip_runtime.h>

// GRU encoder: B=64, T=512, F=64, H=256, D=64.
//   k1: xproj = x @ kernel + bias -> f16 in d_ws, dot2-based GEMM, 4 blk/CU.
//   k2: per-batch scan, 64 blocks x 1024 threads (round-0 structure:
//       gates confined to waves 0-3 so 12/16 waves skip that code).
//       Round-2 deltas: (a) depth-2 h prefetch in the matvec loop,
//       (b) transposed part2 buffer -> gate reads are 6x ds_read_b64,
//       (c) gate waves load x directly from global (coalesced), xrow gone.

typedef _Float16 half2_t __attribute__((ext_vector_type(2)));
typedef _Float16 f16x4_t __attribute__((ext_vector_type(4)));

#define LOG2E 1.4426950408889634f

__device__ __forceinline__ float fast_sigmoid(float x) {
  float e = __builtin_amdgcn_exp2f(-x * LOG2E);
  return __builtin_amdgcn_rcpf(1.0f + e);
}
__device__ __forceinline__ float fast_tanh(float x) {
  float e = __builtin_amdgcn_exp2f(x * (2.0f * LOG2E));
  return 1.0f - 2.0f * __builtin_amdgcn_rcpf(1.0f + e);
}

// ---------------------------------------------------------------------------
// Kernel 1: xproj GEMM.  C(32768x768) = A(32768x64) @ B(64x768) + bias.
// (unchanged)
// ---------------------------------------------------------------------------
__global__ __launch_bounds__(256, 4) void xproj_gemm(
    const float* __restrict__ x, const float* __restrict__ kmat,
    const float* __restrict__ bias, _Float16* __restrict__ xp) {
  __shared__ half2_t As2[32][132];  // [kpair][row]
  __shared__ half2_t Bs2[32][132];  // [kpair][col]
  const int tid = threadIdx.x;
  const int rb = blockIdx.x * 128;
  const int cb = blockIdx.y * 128;

  {
    const int k4 = (tid & 15) * 4;
    const int r0 = tid >> 4;
#pragma unroll
    for (int p = 0; p < 8; ++p) {
      int r = r0 + p * 16;
      float4 v = *(const float4*)(x + (size_t)(rb + r) * 64 + k4);
      half2_t lo, hi;
      lo[0] = (_Float16)v.x; lo[1] = (_Float16)v.y;
      hi[0] = (_Float16)v.z; hi[1] = (_Float16)v.w;
      As2[k4 / 2][r] = lo;
      As2[k4 / 2 + 1][r] = hi;
    }
  }
  {
    const int c4 = (tid & 31) * 4;
    const int kp0 = tid >> 5;
#pragma unroll
    for (int p = 0; p < 4; ++p) {
      int kp = kp0 + p * 8;
      float4 va = *(const float4*)(kmat + (size_t)(2 * kp) * 768 + cb + c4);
      float4 vb = *(const float4*)(kmat + (size_t)(2 * kp + 1) * 768 + cb + c4);
      half2_t o0, o1, o2, o3;
      o0[0] = (_Float16)va.x; o0[1] = (_Float16)vb.x;
      o1[0] = (_Float16)va.y; o1[1] = (_Float16)vb.y;
      o2[0] = (_Float16)va.z; o2[1] = (_Float16)vb.z;
      o3[0] = (_Float16)va.w; o3[1] = (_Float16)vb.w;
      Bs2[kp][c4 + 0] = o0;
      Bs2[kp][c4 + 1] = o1;
      Bs2[kp][c4 + 2] = o2;
      Bs2[kp][c4 + 3] = o3;
    }
  }
  __syncthreads();

  const int tx = tid & 15, ty = tid >> 4;
  const int r0 = ty * 8;
  const int c0 = tx * 4;
  float acc[8][8];
  {
    float4 b0 = *(const float4*)(bias + cb + c0);
    float4 b1 = *(const float4*)(bias + cb + 64 + c0);
    float bz[8] = {b0.x, b0.y, b0.z, b0.w, b1.x, b1.y, b1.z, b1.w};
#pragma unroll
    for (int i = 0; i < 8; ++i)
#pragma unroll
      for (int j = 0; j < 8; ++j) acc[i][j] = bz[j];
  }

#pragma unroll 2
  for (int kp = 0; kp < 32; ++kp) {
    half2_t a2[8], b2[8];
    *(int4*)(&a2[0]) = *(const int4*)(&As2[kp][r0]);
    *(int4*)(&a2[4]) = *(const int4*)(&As2[kp][r0 + 4]);
    *(int2*)(&b2[0]) = *(const int2*)(&Bs2[kp][c0]);
    *(int2*)(&b2[2]) = *(const int2*)(&Bs2[kp][c0 + 2]);
    *(int2*)(&b2[4]) = *(const int2*)(&Bs2[kp][64 + c0]);
    *(int2*)(&b2[6]) = *(const int2*)(&Bs2[kp][64 + c0 + 2]);
#pragma unroll
    for (int i = 0; i < 8; ++i)
#pragma unroll
      for (int j = 0; j < 8; ++j)
        acc[i][j] = __builtin_amdgcn_fdot2(a2[i], b2[j], acc[i][j], false);
  }

#pragma unroll
  for (int i = 0; i < 8; ++i) {
    f16x4_t o0, o1;
#pragma unroll
    for (int j = 0; j < 4; ++j) {
      o0[j] = (_Float16)acc[i][j];
      o1[j] = (_Float16)acc[i][4 + j];
    }
    _Float16* dst = xp + (size_t)(rb + r0 + i) * 768 + cb;
    *(f16x4_t*)(dst + c0) = o0;
    *(f16x4_t*)(dst + 64 + c0) = o1;
  }
}

// ---------------------------------------------------------------------------
// Kernel 2: GRU scan. One block per batch row. 1024 threads = 16 waves.
// Thread (c = tid>>8, col = tid&255) holds W_rec[k in 64c..64c+63] for
// columns {col, col+256, col+512} as 96 packed f16 pairs in VGPRs.
// Matvec: depth-2 int4 prefetch of h from LDS (3 int4 live).
// part2 layout: row (gate*256 + col), row stride 6 floats, entry [c] ->
// matvec writes stride-6 scalars (<=4-way alias), gate wave reads pairs
// as b64.  Gates on waves 0-3 only (others branch over).
// ---------------------------------------------------------------------------
__global__ __launch_bounds__(1024, 4) void gru_scan(
    const _Float16* __restrict__ xp, const float* __restrict__ wr,
    const float* __restrict__ dw, const float* __restrict__ db,
    float* __restrict__ out, float* __restrict__ state) {
  __shared__ float2 part2[768 * 3];  // [(gate*256+col)*3 + pair], 18.4 KB
  __shared__ float hbuf[256];
  __shared__ alignas(16) _Float16 hhalf[256];

  const int tid = threadIdx.x;
  const int b = blockIdx.x;
  const int c = tid >> 8;     // k-chunk 0..3
  const int col = tid & 255;  // output column within gate

  // --- load W_rec fragment into registers as f16 pairs (96 VGPRs)
  half2_t w2[3][32];
#pragma unroll
  for (int q = 0; q < 3; ++q) {
    const float* wp = wr + (size_t)(c * 64) * 768 + col + q * 256;
#pragma unroll
    for (int j = 0; j < 32; ++j) {
      float wa = wp[(size_t)(2 * j) * 768];
      float wb = wp[(size_t)(2 * j + 1) * 768];
      half2_t p;
      p[0] = (_Float16)wa;
      p[1] = (_Float16)wb;
      w2[q][j] = p;
    }
  }

  if (tid < 256) hhalf[tid] = (_Float16)0.0f;
  __syncthreads();

  const _Float16* xpb = xp + (size_t)b * 512 * 768;
  float* outb = out + (size_t)b * 512 * 256;
  const int4* hp2 = (const int4*)hhalf + c * 8;
  float* pw = (float*)part2;
  float hprev = 0.0f;

#pragma unroll 1
  for (int t = 0; t < 512; ++t) {
    // Gate waves only: deferred h(t-1) store + direct coalesced x loads.
    // Issued at step top -> ~full matvec of latency cover; the other 12
    // waves skip this block entirely (no issue cost).
    _Float16 x0 = (_Float16)0.0f, x1 = (_Float16)0.0f, x2 = (_Float16)0.0f;
    if (tid < 256) {
      if (t) outb[(size_t)(t - 1) * 256 + tid] = hprev;
      const _Float16* xr = xpb + (size_t)t * 768 + tid;
      x0 = xr[0];
      x1 = xr[256];
      x2 = xr[512];
    }

    float a0 = 0.0f, a1 = 0.0f, a2 = 0.0f;
    int4 hv = hp2[0];
    int4 hn = hp2[1];
#pragma unroll
    for (int g = 0; g < 8; ++g) {
      __builtin_amdgcn_sched_barrier(1);  // pin ds_reads: prefetch depth 2
      int4 hf = (g < 6) ? hp2[g + 2] : hv;
      half2_t p0 = __builtin_bit_cast(half2_t, hv.x);
      half2_t p1 = __builtin_bit_cast(half2_t, hv.y);
      half2_t p2 = __builtin_bit_cast(half2_t, hv.z);
      half2_t p3 = __builtin_bit_cast(half2_t, hv.w);
      a0 = __builtin_amdgcn_fdot2(p0, w2[0][g * 4 + 0], a0, false);
      a0 = __builtin_amdgcn_fdot2(p1, w2[0][g * 4 + 1], a0, false);
      a0 = __builtin_amdgcn_fdot2(p2, w2[0][g * 4 + 2], a0, false);
      a0 = __builtin_amdgcn_fdot2(p3, w2[0][g * 4 + 3], a0, false);
      a1 = __builtin_amdgcn_fdot2(p0, w2[1][g * 4 + 0], a1, false);
      a1 = __builtin_amdgcn_fdot2(p1, w2[1][g * 4 + 1], a1, false);
      a1 = __builtin_amdgcn_fdot2(p2, w2[1][g * 4 + 2], a1, false);
      a1 = __builtin_amdgcn_fdot2(p3, w2[1][g * 4 + 3], a1, false);
      a2 = __builtin_amdgcn_fdot2(p0, w2[2][g * 4 + 0], a2, false);
      a2 = __builtin_amdgcn_fdot2(p1, w2[2][g * 4 + 1], a2, false);
      a2 = __builtin_amdgcn_fdot2(p2, w2[2][g * 4 + 2], a2, false);
      a2 = __builtin_amdgcn_fdot2(p3, w2[2][g * 4 + 3], a2, false);
      hv = hn;
      hn = hf;
    }
    // Transposed partials: row = gate*256+col, stride 6 floats, entry c.
    pw[col * 6 + c] = a0;
    pw[1536 + col * 6 + c] = a1;
    pw[3072 + col * 6 + c] = a2;
    __syncthreads();

    // --- gates: waves 0..3 only.
    if (tid < 256) {
      const int i = tid;
      float2 z0 = part2[i * 3 + 0];
      float2 z1 = part2[i * 3 + 1];
      float2 r0 = part2[768 + i * 3 + 0];
      float2 r1 = part2[768 + i * 3 + 1];
      float2 h0 = part2[1536 + i * 3 + 0];
      float2 h1 = part2[1536 + i * 3 + 1];
      float rz = (z0.x + z0.y) + (z1.x + z1.y);
      float rr = (r0.x + r0.y) + (r1.x + r1.y);
      float rh = (h0.x + h0.y) + (h1.x + h1.y);
      float z = fast_sigmoid((float)x0 + rz);
      float r = fast_sigmoid((float)x1 + rr);
      float hh = fast_tanh((float)x2 + r * rh);
      float hnew = z * hprev + (1.0f - z) * hh;
      hprev = hnew;
      hhalf[i] = (_Float16)hnew;
    }
    __syncthreads();
  }

  if (tid < 256) {
    outb[(size_t)511 * 256 + tid] = hprev;
    hbuf[tid] = hprev;
  }
  __syncthreads();

  // --- dense head: state[b,:] = tanh(h_last @ dense_w + dense_b)
  if (tid < 64) {
    float acc = db[tid];
#pragma unroll 8
    for (int k = 0; k < 256; ++k) acc = fmaf(hbuf[k], dw[k * 64 + tid], acc);
    state[(size_t)b * 64 + tid] = fast_tanh(acc);
  }
}

// ---------------------------------------------------------------------------
extern "C" void kernel_launch(void* const* d_in, const int* in_sizes, int n_in,
                              void* d_out, int out_size, void* d_ws,
                              size_t ws_size, hipStream_t stream) {
  const float* x = (const float*)d_in[0];     // (64,512,64)
  const float* kmat = (const float*)d_in[1];  // (64,768)
  const float* wr = (const float*)d_in[2];    // (256,768)
  const float* bias = (const float*)d_in[3];  // (768,)
  const float* dw = (const float*)d_in[4];    // (256,64)
  const float* db = (const float*)d_in[5];    // (64,)

  float* out = (float*)d_out;                   // (64,512,256)
  float* state = out + (size_t)64 * 512 * 256;  // (64,64)
  _Float16* xp = (_Float16*)d_ws;               // 64*512*768 f16 = 48 MiB

  dim3 gg(32768 / 128, 768 / 128);
  xproj_gemm<<<gg, 256, 0, stream>>>(x, kmat, bias, xp);
  gru_scan<<<64, 1024, 0, stream>>>(xp, wr, dw, db, out, state);
}